// Round 4
// baseline (535.868 us; speedup 1.0000x reference)
//
#include <hip/hip_runtime.h>
#include <hip/hip_bf16.h>
#include <stdint.h>

// Problem dims (fixed): N=4, L=4096, E=1024, H=1024
#define NB 4
#define LS 4096
#define ED 1024
#define HD 1024
#define MR (NB * LS)            // 16384 flattened rows
#define SCALE_S (1.0f / 64.0f)  // 1/sqrt(L)

typedef __attribute__((ext_vector_type(8))) short bf16x8;  // 8 bf16 (4 VGPRs)
typedef __attribute__((ext_vector_type(8))) int   i32x8;   // 32 fp8 bytes (8 VGPRs)
typedef __attribute__((ext_vector_type(4))) float f32x4;

__device__ __forceinline__ unsigned short f2bf(float f) {
    union { float f; uint32_t u; } x; x.f = f;
    uint32_t r = x.u + 0x7fffu + ((x.u >> 16) & 1u);  // RNE
    return (unsigned short)(r >> 16);
}

// async global->LDS, 16B/lane; LDS dest = wave-uniform base + lane*16
__device__ __forceinline__ void load_lds16(const void* g, void* s) {
    __builtin_amdgcn_global_load_lds(
        (const __attribute__((address_space(1))) void*)g,
        (__attribute__((address_space(3))) void*)s, 16, 0, 0);
}

// ---------------- casts ----------------
__global__ void __launch_bounds__(256) cast_x_k(
    const float4* __restrict__ src, ushort4* __restrict__ dst)
{
    const int i = blockIdx.x * 256 + threadIdx.x;
    const float4 v = src[i];
    ushort4 o; o.x = f2bf(v.x); o.y = f2bf(v.y); o.z = f2bf(v.z); o.w = f2bf(v.w);
    dst[i] = o;
}

// pack Wq,Wk,Wv -> contiguous bf16 [3072 x 1024]
__global__ void __launch_bounds__(256) cast_w_k(
    const float4* __restrict__ wq, const float4* __restrict__ wk,
    const float4* __restrict__ wv, ushort4* __restrict__ dst)
{
    const int i = blockIdx.x * 256 + threadIdx.x;  // 0 .. 3*2^18-1
    const int s = i >> 18, j = i & 0x3ffff;
    const float4 v = (s == 0 ? wq : s == 1 ? wk : wv)[j];
    ushort4 o; o.x = f2bf(v.x); o.y = f2bf(v.y); o.z = f2bf(v.z); o.w = f2bf(v.w);
    dst[i] = o;
}

// ---------------- fused QKV projection ----------------
// One block computes Q,K,V tiles for (128 rows x 128 H-cols): X-tile staged once
// per k-iter feeds 48 MFMAs (3 projections). Epilogue: Q,K -> tiled fp8 +
// fp32 diagonal partials (atomicAdd); V -> fp32 into d_out.
// MFMA operands swapped (bF first): lane&15 = C row, regs = 4 consecutive cols.
// fp8 tiled layout: addr = (row>>4)*16384 + (col>>4)*256 + (row&15)*16 + (col&15)
__global__ void __launch_bounds__(256, 2)
gemm_qkv_fused(const unsigned short* __restrict__ A,   // Xb [16384 x 1024]
               const unsigned short* __restrict__ W,   // Wall [3072 x 1024]
               const float* __restrict__ bq, const float* __restrict__ bk,
               const float* __restrict__ bv,
               unsigned char* __restrict__ Qf8t, unsigned char* __restrict__ Kf8t,
               float* __restrict__ outV, float* __restrict__ diag)
{
    __shared__ unsigned short As[128 * 32];
    __shared__ unsigned short Ws0[128 * 32];
    __shared__ unsigned short Ws1[128 * 32];
    __shared__ unsigned short Ws2[128 * 32];

    const int t = threadIdx.x;
    const int wid = t >> 6, lane = t & 63, quad = lane >> 4, l16 = lane & 15;
    const int m0 = (wid >> 1) * 64, n0 = (wid & 1) * 64;
    const long blockM = (long)blockIdx.y * 128;
    const int blockN = blockIdx.x * 128;  // 0..896 within H

    const char* a_g  = (const char*)(A + (blockM + (t >> 2)) * (size_t)ED + (size_t)((t & 3) * 8));
    const char* w0_g = (const char*)(W + ((size_t)blockN + (t >> 2)) * ED + (size_t)((t & 3) * 8));
    const char* w1_g = w0_g + (size_t)1024 * ED * 2;
    const char* w2_g = w1_g + (size_t)1024 * ED * 2;
    const size_t half = (size_t)64 * ED * 2;

    char* a_s0 = (char*)As  + wid * 1024;
    char* w0_s = (char*)Ws0 + wid * 1024;
    char* w1_s = (char*)Ws1 + wid * 1024;
    char* w2_s = (char*)Ws2 + wid * 1024;

    f32x4 acc[3][4][4] = {};

    for (int kt = 0; kt < ED; kt += 32) {
        const int kb = kt * 2;
        load_lds16(a_g  + kb,        a_s0);
        load_lds16(a_g  + kb + half, a_s0 + 4096);
        load_lds16(w0_g + kb,        w0_s);
        load_lds16(w0_g + kb + half, w0_s + 4096);
        load_lds16(w1_g + kb,        w1_s);
        load_lds16(w1_g + kb + half, w1_s + 4096);
        load_lds16(w2_g + kb,        w2_s);
        load_lds16(w2_g + kb + half, w2_s + 4096);
        __syncthreads();

        bf16x8 aF[4];
        const char* AsB = (const char*)As;
#pragma unroll
        for (int mf = 0; mf < 4; mf++)
            aF[mf] = *(const bf16x8*)(AsB + ((m0 + mf * 16 + l16) * 32 + quad * 8) * 2);

#pragma unroll
        for (int p = 0; p < 3; p++) {
            const char* WsB = (const char*)(p == 0 ? Ws0 : p == 1 ? Ws1 : Ws2);
            bf16x8 bF[4];
#pragma unroll
            for (int nf = 0; nf < 4; nf++)
                bF[nf] = *(const bf16x8*)(WsB + ((n0 + nf * 16 + l16) * 32 + quad * 8) * 2);
#pragma unroll
            for (int mf = 0; mf < 4; mf++)
#pragma unroll
                for (int nf = 0; nf < 4; nf++)
                    acc[p][mf][nf] = __builtin_amdgcn_mfma_f32_16x16x32_bf16(
                        bF[nf], aF[mf], acc[p][mf][nf], 0, 0, 0);  // swapped
        }
        __syncthreads();
    }

    // epilogue: fp8 Q/K (tiled), fp32 V, fp32 diag partials
    float dp[4] = {0.f, 0.f, 0.f, 0.f};
#pragma unroll
    for (int nf = 0; nf < 4; nf++) {
        const int col = blockN + n0 + nf * 16 + quad * 4;  // 4 consecutive H-cols
        const float4 q4 = *(const float4*)(bq + col);
        const float4 k4 = *(const float4*)(bk + col);
        const float4 v4 = *(const float4*)(bv + col);
#pragma unroll
        for (int mf = 0; mf < 4; mf++) {
            const size_t row = (size_t)(blockM + m0 + mf * 16 + l16);
            const float vq0 = acc[0][mf][nf][0] + q4.x, vq1 = acc[0][mf][nf][1] + q4.y;
            const float vq2 = acc[0][mf][nf][2] + q4.z, vq3 = acc[0][mf][nf][3] + q4.w;
            const float vk0 = acc[1][mf][nf][0] + k4.x, vk1 = acc[1][mf][nf][1] + k4.y;
            const float vk2 = acc[1][mf][nf][2] + k4.z, vk3 = acc[1][mf][nf][3] + k4.w;
            const float vv0 = acc[2][mf][nf][0] + v4.x, vv1 = acc[2][mf][nf][1] + v4.y;
            const float vv2 = acc[2][mf][nf][2] + v4.z, vv3 = acc[2][mf][nf][3] + v4.w;
            uint32_t uq = 0, uk = 0;
            uq = __builtin_amdgcn_cvt_pk_fp8_f32(vq0, vq1, uq, false);
            uq = __builtin_amdgcn_cvt_pk_fp8_f32(vq2, vq3, uq, true);
            uk = __builtin_amdgcn_cvt_pk_fp8_f32(vk0, vk1, uk, false);
            uk = __builtin_amdgcn_cvt_pk_fp8_f32(vk2, vk3, uk, true);
            const size_t f8 = (row >> 4) * 16384 + (size_t)(col >> 4) * 256
                            + (row & 15) * 16 + (col & 15);
            *(uint32_t*)(Qf8t + f8) = uq;
            *(uint32_t*)(Kf8t + f8) = uk;
            float4 o; o.x = vv0; o.y = vv1; o.z = vv2; o.w = vv3;
            *(float4*)(outV + row * 1024 + col) = o;
            dp[mf] += vq0 * vk0 + vq1 * vk1 + vq2 * vk2 + vq3 * vk3;
        }
    }
#pragma unroll
    for (int mf = 0; mf < 4; mf++) {
        float d = dp[mf];
        d += __shfl_xor(d, 16);
        d += __shfl_xor(d, 32);
        if (quad == 0)
            atomicAdd(&diag[blockM + m0 + mf * 16 + l16], d);
    }
}

// ---------------- fp8 MX denominator GEMM ----------------
// denom[n,b] += sum_a exp((Q[n,a]·K[n,b])/64). Tile 256(M) x 128(N), 4 waves of
// 64x128 -> 32 MFMAs per wave-iter (2x barrier amortization vs 128x128).
__global__ void __launch_bounds__(256, 2)
gemm_f8_denom(const unsigned char* __restrict__ Qt,
              const unsigned char* __restrict__ Kt,
              float* __restrict__ denom)
{
    __shared__ __align__(16) unsigned char As[32768];  // 256 rows: 16 groups x 2KB
    __shared__ __align__(16) unsigned char Bs[16384];  // 128 rows:  8 groups x 2KB

    const int t = threadIdx.x;
    const int wid = t >> 6, lane = t & 63, quad = lane >> 4, l16 = lane & 15;
    const size_t zoff = (size_t)blockIdx.z * LS * (size_t)HD;
    const int blockM = blockIdx.y * 256;
    const int blockN = blockIdx.x * 128;
    const unsigned char* Ag = Qt + zoff + (size_t)(blockM >> 4) * 16384 + (size_t)lane * 16;
    const unsigned char* Bg = Kt + zoff + (size_t)(blockN >> 4) * 16384 + (size_t)lane * 16;
    float* dn = denom + (size_t)blockIdx.z * LS;

    f32x4 acc[4][8] = {};

    for (int kt = 0; kt < 8; kt++) {
        const size_t ko = (size_t)kt * 2048;
#pragma unroll
        for (int j = 0; j < 8; j++) {       // A: 32 x 1KB windows, 8 per wave
            const int i = wid * 8 + j;
            load_lds16(Ag + ko + (size_t)(i >> 1) * 16384 + (size_t)(i & 1) * 1024,
                       (char*)As + i * 1024);
        }
#pragma unroll
        for (int j = 0; j < 4; j++) {       // B: 16 x 1KB windows, 4 per wave
            const int i = wid * 4 + j;
            load_lds16(Bg + ko + (size_t)(i >> 1) * 16384 + (size_t)(i & 1) * 1024,
                       (char*)Bs + i * 1024);
        }
        __syncthreads();

        i32x8 aF[4], bF[8];
#pragma unroll
        for (int mf = 0; mf < 4; mf++) {    // wave rows: wid*64 + mf*16 + l16
            const int base = (wid * 4 + mf) * 2048 + quad * 512 + l16 * 16;
            const int4 lo = *(const int4*)(As + base);
            const int4 hi = *(const int4*)(As + base + 256);
            aF[mf][0] = lo.x; aF[mf][1] = lo.y; aF[mf][2] = lo.z; aF[mf][3] = lo.w;
            aF[mf][4] = hi.x; aF[mf][5] = hi.y; aF[mf][6] = hi.z; aF[mf][7] = hi.w;
        }
#pragma unroll
        for (int nf = 0; nf < 8; nf++) {
            const int base = nf * 2048 + quad * 512 + l16 * 16;
            const int4 lo = *(const int4*)(Bs + base);
            const int4 hi = *(const int4*)(Bs + base + 256);
            bF[nf][0] = lo.x; bF[nf][1] = lo.y; bF[nf][2] = lo.z; bF[nf][3] = lo.w;
            bF[nf][4] = hi.x; bF[nf][5] = hi.y; bF[nf][6] = hi.z; bF[nf][7] = hi.w;
        }
#pragma unroll
        for (int mf = 0; mf < 4; mf++)
#pragma unroll
            for (int nf = 0; nf < 8; nf++)
                acc[mf][nf] = __builtin_amdgcn_mfma_scale_f32_16x16x128_f8f6f4(
                    aF[mf], bF[nf], acc[mf][nf],
                    0, 0,              // cbsz=FP8, blgp=FP8
                    0, 0x7f7f7f7f,     // scale_a = 1.0 (E8M0 127)
                    0, 0x7f7f7f7f);    // scale_b = 1.0
        __syncthreads();
    }

    // C/D: col = lane&15 (K-row -> output col), rows = quad*4+reg
#pragma unroll
    for (int nf = 0; nf < 8; nf++) {
        float s = 0.f;
#pragma unroll
        for (int mf = 0; mf < 4; mf++)
#pragma unroll
            for (int r = 0; r < 4; r++)
                s += __expf(acc[mf][nf][r] * SCALE_S);
        s += __shfl_xor(s, 16);
        s += __shfl_xor(s, 32);
        if (quad == 0)
            atomicAdd(&dn[blockN + nf * 16 + l16], s);
    }
}

// ---------------- finalize: out[row,:] *= exp(diag[row]/64)/denom[row] ----------------
__global__ void __launch_bounds__(256) finalize_k(
    float* __restrict__ out, const float* __restrict__ diag,
    const float* __restrict__ denom)
{
    const int row = blockIdx.x;
    const float sc = __expf(diag[row] * SCALE_S) / denom[row];
    float4* p = (float4*)(out + (size_t)row * HD) + threadIdx.x;
    float4 v = *p;
    v.x *= sc; v.y *= sc; v.z *= sc; v.w *= sc;
    *p = v;
}

extern "C" void kernel_launch(void* const* d_in, const int* in_sizes, int n_in,
                              void* d_out, int out_size, void* d_ws, size_t ws_size,
                              hipStream_t stream)
{
    (void)in_sizes; (void)n_in; (void)out_size; (void)ws_size;
    const float* X  = (const float*)d_in[0];
    const float* Wq = (const float*)d_in[1];
    const float* bq = (const float*)d_in[2];
    const float* Wk = (const float*)d_in[3];
    const float* bk = (const float*)d_in[4];
    const float* Wv = (const float*)d_in[5];
    const float* bv = (const float*)d_in[6];
    float* out = (float*)d_out;

    // workspace layout (~73.5 MB)
    char* p = (char*)d_ws;
    unsigned short* Xb   = (unsigned short*)p; p += (size_t)MR * ED * 2;   // 33.55 MB
    unsigned short* Wall = (unsigned short*)p; p += (size_t)3072 * ED * 2; //  6.29 MB
    unsigned char*  Qf8t = (unsigned char*)p;  p += (size_t)MR * HD;       // 16.78 MB (tiled)
    unsigned char*  Kf8t = (unsigned char*)p;  p += (size_t)MR * HD;       // 16.78 MB (tiled)
    float* diag  = (float*)p; p += (size_t)MR * 4;                         // adjacent:
    float* denom = (float*)p; p += (size_t)MR * 4;                         // one memset

    // 1) casts
    cast_x_k<<<MR * ED / 4 / 256, 256, 0, stream>>>((const float4*)X, (ushort4*)Xb);
    cast_w_k<<<3 * ED * ED / 4 / 256, 256, 0, stream>>>(
        (const float4*)Wq, (const float4*)Wk, (const float4*)Wv, (ushort4*)Wall);

    // 2) zero diag+denom (atomic accumulators)
    hipMemsetAsync(diag, 0, 2 * MR * sizeof(float), stream);

    // 3) fused QKV projection (Q,K -> tiled fp8 + diag partials; V -> fp32 in d_out)
    dim3 blk(256);
    dim3 gqkv(HD / 128, MR / 128);
    gemm_qkv_fused<<<gqkv, blk, 0, stream>>>(Xb, Wall, bq, bk, bv, Qf8t, Kf8t, out, diag);

    // 4) column denominators via MX-fp8 GEMM (256x128 tiles)
    dim3 gden(LS / 128, LS / 256, NB);
    gemm_f8_denom<<<gden, blk, 0, stream>>>(Qf8t, Kf8t, denom);

    // 5) out *= exp(diag/64)/denom (in place on V)
    finalize_k<<<MR, blk, 0, stream>>>(out, diag, denom);
}

// Round 5
// 360.696 us; speedup vs baseline: 1.4857x; 1.4857x over previous
//
#include <hip/hip_runtime.h>
#include <hip/hip_bf16.h>
#include <stdint.h>

// Problem dims (fixed): N=4, L=4096, E=1024, H=1024
#define NB 4
#define LS 4096
#define ED 1024
#define HD 1024
#define MR (NB * LS)            // 16384 flattened rows
#define SCALE_S (1.0f / 64.0f)  // 1/sqrt(L)

typedef __attribute__((ext_vector_type(8))) short bf16x8;  // 8 bf16 (4 VGPRs)
typedef __attribute__((ext_vector_type(8))) int   i32x8;   // 32 fp8 bytes (8 VGPRs)
typedef __attribute__((ext_vector_type(4))) float f32x4;

__device__ __forceinline__ unsigned short f2bf(float f) {
    union { float f; uint32_t u; } x; x.f = f;
    uint32_t r = x.u + 0x7fffu + ((x.u >> 16) & 1u);  // RNE
    return (unsigned short)(r >> 16);
}

// async global->LDS, 16B/lane; LDS dest = wave-uniform base + lane*16
__device__ __forceinline__ void load_lds16(const void* g, void* s) {
    __builtin_amdgcn_global_load_lds(
        (const __attribute__((address_space(1))) void*)g,
        (__attribute__((address_space(3))) void*)s, 16, 0, 0);
}

// ---------------- merged cast: X (16384x1024) and Wq|Wk|Wv -> Wall ----------------
#define XCHUNKS (MR * ED / 4)        // 4194304 float4s
#define WCHUNKS (3 * ED * ED / 4)    // 786432 float4s
__global__ void __launch_bounds__(256) cast_all_k(
    const float4* __restrict__ X, const float4* __restrict__ wq,
    const float4* __restrict__ wk, const float4* __restrict__ wv,
    ushort4* __restrict__ Xb, ushort4* __restrict__ Wall)
{
    const int i = blockIdx.x * 256 + threadIdx.x;
    if (i < XCHUNKS) {
        const float4 v = X[i];
        ushort4 o; o.x = f2bf(v.x); o.y = f2bf(v.y); o.z = f2bf(v.z); o.w = f2bf(v.w);
        Xb[i] = o;
    } else if (i < XCHUNKS + WCHUNKS) {
        const int j = i - XCHUNKS;
        const int s = j >> 18, jj = j & 0x3ffff;
        const float4 v = (s == 0 ? wq : s == 1 ? wk : wv)[jj];
        ushort4 o; o.x = f2bf(v.x); o.y = f2bf(v.y); o.z = f2bf(v.z); o.w = f2bf(v.w);
        Wall[j] = o;
    }
}

// ---------------- fused Q+K projection ----------------
// One block: Q-tile AND K-tile for (128 rows x 128 H-cols). X staged once per
// k-iter feeds 32 MFMAs. Epilogue: tiled fp8 Q/K + exact fp32 diag partials.
// MFMA operands swapped (bF first): lane&15 = C row, regs = 4 consecutive cols.
// fp8 tiled layout: addr = (row>>4)*16384 + (col>>4)*256 + (row&15)*16 + (col&15)
__global__ void __launch_bounds__(256, 2)
gemm_qk_fused(const unsigned short* __restrict__ A,   // Xb [16384 x 1024]
              const unsigned short* __restrict__ W,   // Wall [3072 x 1024]
              const float* __restrict__ bq, const float* __restrict__ bk,
              unsigned char* __restrict__ Qf8t, unsigned char* __restrict__ Kf8t,
              float* __restrict__ diag)
{
    __shared__ unsigned short As[128 * 32];
    __shared__ unsigned short Ws0[128 * 32];
    __shared__ unsigned short Ws1[128 * 32];

    const int t = threadIdx.x;
    const int wid = t >> 6, lane = t & 63, quad = lane >> 4, l16 = lane & 15;
    const int m0 = (wid >> 1) * 64, n0 = (wid & 1) * 64;
    const long blockM = (long)blockIdx.y * 128;
    const int blockN = blockIdx.x * 128;  // 0..896 within H

    const char* a_g  = (const char*)(A + (blockM + (t >> 2)) * (size_t)ED + (size_t)((t & 3) * 8));
    const char* w0_g = (const char*)(W + ((size_t)blockN + (t >> 2)) * ED + (size_t)((t & 3) * 8));
    const char* w1_g = w0_g + (size_t)1024 * ED * 2;  // Wk block
    const size_t half = (size_t)64 * ED * 2;

    char* a_s0 = (char*)As  + wid * 1024;
    char* w0_s = (char*)Ws0 + wid * 1024;
    char* w1_s = (char*)Ws1 + wid * 1024;

    f32x4 acc[2][4][4] = {};

    for (int kt = 0; kt < ED; kt += 32) {
        const int kb = kt * 2;
        load_lds16(a_g  + kb,        a_s0);
        load_lds16(a_g  + kb + half, a_s0 + 4096);
        load_lds16(w0_g + kb,        w0_s);
        load_lds16(w0_g + kb + half, w0_s + 4096);
        load_lds16(w1_g + kb,        w1_s);
        load_lds16(w1_g + kb + half, w1_s + 4096);
        __syncthreads();

        bf16x8 aF[4];
        const char* AsB = (const char*)As;
#pragma unroll
        for (int mf = 0; mf < 4; mf++)
            aF[mf] = *(const bf16x8*)(AsB + ((m0 + mf * 16 + l16) * 32 + quad * 8) * 2);

#pragma unroll
        for (int p = 0; p < 2; p++) {
            const char* WsB = (const char*)(p == 0 ? Ws0 : Ws1);
            bf16x8 bF[4];
#pragma unroll
            for (int nf = 0; nf < 4; nf++)
                bF[nf] = *(const bf16x8*)(WsB + ((n0 + nf * 16 + l16) * 32 + quad * 8) * 2);
#pragma unroll
            for (int mf = 0; mf < 4; mf++)
#pragma unroll
                for (int nf = 0; nf < 4; nf++)
                    acc[p][mf][nf] = __builtin_amdgcn_mfma_f32_16x16x32_bf16(
                        bF[nf], aF[mf], acc[p][mf][nf], 0, 0, 0);  // swapped
        }
        __syncthreads();
    }

    // epilogue: tiled fp8 Q/K + fp32 diag partials
    float dp[4] = {0.f, 0.f, 0.f, 0.f};
#pragma unroll
    for (int nf = 0; nf < 4; nf++) {
        const int col = blockN + n0 + nf * 16 + quad * 4;  // 4 consecutive H-cols
        const float4 q4 = *(const float4*)(bq + col);
        const float4 k4 = *(const float4*)(bk + col);
#pragma unroll
        for (int mf = 0; mf < 4; mf++) {
            const size_t row = (size_t)(blockM + m0 + mf * 16 + l16);
            const float vq0 = acc[0][mf][nf][0] + q4.x, vq1 = acc[0][mf][nf][1] + q4.y;
            const float vq2 = acc[0][mf][nf][2] + q4.z, vq3 = acc[0][mf][nf][3] + q4.w;
            const float vk0 = acc[1][mf][nf][0] + k4.x, vk1 = acc[1][mf][nf][1] + k4.y;
            const float vk2 = acc[1][mf][nf][2] + k4.z, vk3 = acc[1][mf][nf][3] + k4.w;
            uint32_t uq = 0, uk = 0;
            uq = __builtin_amdgcn_cvt_pk_fp8_f32(vq0, vq1, uq, false);
            uq = __builtin_amdgcn_cvt_pk_fp8_f32(vq2, vq3, uq, true);
            uk = __builtin_amdgcn_cvt_pk_fp8_f32(vk0, vk1, uk, false);
            uk = __builtin_amdgcn_cvt_pk_fp8_f32(vk2, vk3, uk, true);
            const size_t f8 = (row >> 4) * 16384 + (size_t)(col >> 4) * 256
                            + (row & 15) * 16 + (col & 15);
            *(uint32_t*)(Qf8t + f8) = uq;
            *(uint32_t*)(Kf8t + f8) = uk;
            dp[mf] += vq0 * vk0 + vq1 * vk1 + vq2 * vk2 + vq3 * vk3;
        }
    }
#pragma unroll
    for (int mf = 0; mf < 4; mf++) {
        float d = dp[mf];
        d += __shfl_xor(d, 16);
        d += __shfl_xor(d, 32);
        if (quad == 0)
            atomicAdd(&diag[blockM + m0 + mf * 16 + l16], d);
    }
}

// ---------------- V projection (lean): V = Xb * Wv^T + bv -> fp32 d_out ----------------
__global__ void __launch_bounds__(256)
gemm_v(const unsigned short* __restrict__ A,   // Xb
       const unsigned short* __restrict__ Wv,  // Wall + 2*1024*1024
       const float* __restrict__ bv, float* __restrict__ outV)
{
    __shared__ unsigned short As[128 * 32];
    __shared__ unsigned short Bs[128 * 32];

    const int t = threadIdx.x;
    const int wid = t >> 6, lane = t & 63, quad = lane >> 4, l16 = lane & 15;
    const int m0 = (wid >> 1) * 64, n0 = (wid & 1) * 64;
    const long blockM = (long)blockIdx.y * 128;
    const int blockN = blockIdx.x * 128;

    const char* a_g = (const char*)(A  + (blockM + (t >> 2)) * (size_t)ED + (size_t)((t & 3) * 8));
    const char* b_g = (const char*)(Wv + ((size_t)blockN + (t >> 2)) * ED + (size_t)((t & 3) * 8));
    const size_t half = (size_t)64 * ED * 2;

    char* a_s0 = (char*)As + wid * 1024;
    char* b_s0 = (char*)Bs + wid * 1024;

    f32x4 acc[4][4] = {};

    for (int kt = 0; kt < ED; kt += 32) {
        const int kb = kt * 2;
        load_lds16(a_g + kb,        a_s0);
        load_lds16(a_g + kb + half, a_s0 + 4096);
        load_lds16(b_g + kb,        b_s0);
        load_lds16(b_g + kb + half, b_s0 + 4096);
        __syncthreads();

        bf16x8 aF[4], bF[4];
        const char* AsB = (const char*)As;
        const char* BsB = (const char*)Bs;
#pragma unroll
        for (int mf = 0; mf < 4; mf++)
            aF[mf] = *(const bf16x8*)(AsB + ((m0 + mf * 16 + l16) * 32 + quad * 8) * 2);
#pragma unroll
        for (int nf = 0; nf < 4; nf++)
            bF[nf] = *(const bf16x8*)(BsB + ((n0 + nf * 16 + l16) * 32 + quad * 8) * 2);
#pragma unroll
        for (int mf = 0; mf < 4; mf++)
#pragma unroll
            for (int nf = 0; nf < 4; nf++)
                acc[mf][nf] = __builtin_amdgcn_mfma_f32_16x16x32_bf16(
                    bF[nf], aF[mf], acc[mf][nf], 0, 0, 0);  // swapped
        __syncthreads();
    }

#pragma unroll
    for (int mf = 0; mf < 4; mf++) {
        const size_t row = (size_t)(blockM + m0 + mf * 16 + l16);
#pragma unroll
        for (int nf = 0; nf < 4; nf++) {
            const int col = blockN + n0 + nf * 16 + quad * 4;
            const float4 b4 = *(const float4*)(bv + col);
            float4 o;
            o.x = acc[mf][nf][0] + b4.x; o.y = acc[mf][nf][1] + b4.y;
            o.z = acc[mf][nf][2] + b4.z; o.w = acc[mf][nf][3] + b4.w;
            *(float4*)(outV + row * 1024 + col) = o;
        }
    }
}

// ---------------- fp8 MX denominator GEMM (R3-proven 128x128) ----------------
__global__ void __launch_bounds__(256)
gemm_f8_denom(const unsigned char* __restrict__ Qt,
              const unsigned char* __restrict__ Kt,
              float* __restrict__ denom)
{
    __shared__ __align__(16) unsigned char As[16384];
    __shared__ __align__(16) unsigned char Bs[16384];

    const int t = threadIdx.x;
    const int wid = t >> 6, lane = t & 63, quad = lane >> 4, l16 = lane & 15;
    const int m0 = (wid >> 1) * 64, n0 = (wid & 1) * 64;
    const size_t zoff = (size_t)blockIdx.z * LS * (size_t)HD;
    const unsigned char* A = Qt + zoff;
    const unsigned char* B = Kt + zoff;
    float* dn = denom + (size_t)blockIdx.z * LS;
    const int blockM = blockIdx.y * 128;
    const int blockN = blockIdx.x * 128;

    size_t aoff[4], boff[4];
#pragma unroll
    for (int j = 0; j < 4; j++) {
        const int iw = wid * 4 + j;
        const size_t lo = (size_t)((iw & 1) * 4 + (lane >> 4)) * 256 + (size_t)(lane & 15) * 16;
        aoff[j] = ((size_t)(blockM >> 4) + (iw >> 1)) * 16384 + lo;
        boff[j] = ((size_t)(blockN >> 4) + (iw >> 1)) * 16384 + lo;
    }

    f32x4 acc[4][4] = {};

    for (int kt = 0; kt < 8; kt++) {           // 8 k-tiles of 128 bytes
        const size_t ko = (size_t)kt * 2048;
#pragma unroll
        for (int j = 0; j < 4; j++) {
            load_lds16(A + aoff[j] + ko, (char*)As + (wid * 4 + j) * 1024);
            load_lds16(B + boff[j] + ko, (char*)Bs + (wid * 4 + j) * 1024);
        }
        __syncthreads();

        i32x8 aF[4], bF[4];
#pragma unroll
        for (int mf = 0; mf < 4; mf++) {
            const int base = (((m0 >> 4) + mf) * 2048) + quad * 512 + l16 * 16;
            const int4 lo = *(const int4*)(As + base);
            const int4 hi = *(const int4*)(As + base + 256);
            aF[mf][0] = lo.x; aF[mf][1] = lo.y; aF[mf][2] = lo.z; aF[mf][3] = lo.w;
            aF[mf][4] = hi.x; aF[mf][5] = hi.y; aF[mf][6] = hi.z; aF[mf][7] = hi.w;
        }
#pragma unroll
        for (int nf = 0; nf < 4; nf++) {
            const int base = (((n0 >> 4) + nf) * 2048) + quad * 512 + l16 * 16;
            const int4 lo = *(const int4*)(Bs + base);
            const int4 hi = *(const int4*)(Bs + base + 256);
            bF[nf][0] = lo.x; bF[nf][1] = lo.y; bF[nf][2] = lo.z; bF[nf][3] = lo.w;
            bF[nf][4] = hi.x; bF[nf][5] = hi.y; bF[nf][6] = hi.z; bF[nf][7] = hi.w;
        }
#pragma unroll
        for (int mf = 0; mf < 4; mf++)
#pragma unroll
            for (int nf = 0; nf < 4; nf++)
                acc[mf][nf] = __builtin_amdgcn_mfma_scale_f32_16x16x128_f8f6f4(
                    aF[mf], bF[nf], acc[mf][nf],
                    0, 0,              // cbsz=FP8, blgp=FP8
                    0, 0x7f7f7f7f,     // scale_a = 1.0 (E8M0 127)
                    0, 0x7f7f7f7f);    // scale_b = 1.0
        __syncthreads();
    }

    // C/D: col = lane&15 (K-row -> output col), rows = quad*4+reg
#pragma unroll
    for (int nf = 0; nf < 4; nf++) {
        float s = 0.f;
#pragma unroll
        for (int mf = 0; mf < 4; mf++)
#pragma unroll
            for (int r = 0; r < 4; r++)
                s += __expf(acc[mf][nf][r] * SCALE_S);
        s += __shfl_xor(s, 16);
        s += __shfl_xor(s, 32);
        if (quad == 0)
            atomicAdd(&dn[blockN + n0 + nf * 16 + l16], s);
    }
}

// ---------------- finalize: out[row,:] *= exp(diag[row]/64)/denom[row] ----------------
__global__ void __launch_bounds__(256) finalize_k(
    float* __restrict__ out, const float* __restrict__ diag,
    const float* __restrict__ denom)
{
    const int row = blockIdx.x;
    const float sc = __expf(diag[row] * SCALE_S) / denom[row];
    float4* p = (float4*)(out + (size_t)row * HD) + threadIdx.x;
    float4 v = *p;
    v.x *= sc; v.y *= sc; v.z *= sc; v.w *= sc;
    *p = v;
}

extern "C" void kernel_launch(void* const* d_in, const int* in_sizes, int n_in,
                              void* d_out, int out_size, void* d_ws, size_t ws_size,
                              hipStream_t stream)
{
    (void)in_sizes; (void)n_in; (void)out_size; (void)ws_size;
    const float* X  = (const float*)d_in[0];
    const float* Wq = (const float*)d_in[1];
    const float* bq = (const float*)d_in[2];
    const float* Wk = (const float*)d_in[3];
    const float* bk = (const float*)d_in[4];
    const float* Wv = (const float*)d_in[5];
    const float* bv = (const float*)d_in[6];
    float* out = (float*)d_out;

    // workspace layout (~73.5 MB)
    char* p = (char*)d_ws;
    unsigned short* Xb   = (unsigned short*)p; p += (size_t)MR * ED * 2;   // 33.55 MB
    unsigned short* Wall = (unsigned short*)p; p += (size_t)3072 * ED * 2; //  6.29 MB
    unsigned char*  Qf8t = (unsigned char*)p;  p += (size_t)MR * HD;       // 16.78 MB (tiled)
    unsigned char*  Kf8t = (unsigned char*)p;  p += (size_t)MR * HD;       // 16.78 MB (tiled)
    float* diag  = (float*)p; p += (size_t)MR * 4;                         // adjacent:
    float* denom = (float*)p; p += (size_t)MR * 4;                         // one memset

    dim3 blk(256);

    // 1) merged casts (X -> bf16, Wq|Wk|Wv -> Wall bf16)
    cast_all_k<<<(XCHUNKS + WCHUNKS + 255) / 256, blk, 0, stream>>>(
        (const float4*)X, (const float4*)Wq, (const float4*)Wk, (const float4*)Wv,
        (ushort4*)Xb, (ushort4*)Wall);

    // 2) zero diag+denom (atomic accumulators)
    hipMemsetAsync(diag, 0, 2 * MR * sizeof(float), stream);

    // 3) fused Q+K projection -> tiled fp8 + fp32 diag partials
    dim3 gqk(HD / 128, MR / 128);
    gemm_qk_fused<<<gqk, blk, 0, stream>>>(Xb, Wall, bq, bk, Qf8t, Kf8t, diag);

    // 4) V projection -> fp32 directly into d_out
    gemm_v<<<gqk, blk, 0, stream>>>(Xb, Wall + (size_t)2048 * ED, bv, out);

    // 5) column denominators via MX-fp8 GEMM (128x128, R3-proven)
    dim3 gden(LS / 128, LS / 128, NB);
    gemm_f8_denom<<<gden, blk, 0, stream>>>(Qf8t, Kf8t, denom);

    // 6) out *= exp(diag/64)/denom (in place on V)
    finalize_k<<<MR, blk, 0, stream>>>(out, diag, denom);
}